// Round 4
// baseline (432.285 us; speedup 1.0000x reference)
//
#include <hip/hip_runtime.h>
#include <hip/hip_fp16.h>
#include <math.h>

#define NB 16
#define NA 720
#define ND 1024
#define NH 512
#define NW 512

#define TW 64      // tile width  (x)
#define TH 8       // tile height (y)
#define PXT 2      // x-subtiles per thread (8x8 lane map: k steps x by 8)
#define NBT 8      // batches per block
#define WINN 68    // window entries (span <= 63|c|+7|s| + 3 ~ 66.4)
#define GROUP 16   // angles per fp16-accumulate group (720 = 45*16)

typedef __fp16 h2vec __attribute__((ext_vector_type(2)));

__device__ __forceinline__ uint32_t pkrtz_u32(float a, float b) {
    union { h2vec h; uint32_t u; } v;
    v.h = __builtin_amdgcn_cvt_pkrtz(a, b);   // one v_cvt_pkrtz_f16_f32
    return v.u;
}
__device__ __forceinline__ __half2 u32_to_h2(uint32_t u) {
    union { uint32_t u; __half2 h; } v; v.u = u; return v.h;
}
__device__ __forceinline__ uint32_t h2_to_u32(__half2 h) {
    union { __half2 h; uint32_t u; } v; v.h = h; return v.u;
}

// ---------------------------------------------------------------------------
// Kernel 0: per-(tile-position, angle) parameter table. 512 positions x 720
// angles x 16B. Entry: (c, s, 511.5-base, bits(a*ND+base)). Computed once so
// the backproj kernel reads params via uniform s_load (SMEM pipe) instead of
// re-deriving them in VALU every angle (no scalar FP unit on CDNA).
// ---------------------------------------------------------------------------
__global__ __launch_bounds__(768) void prep_kernel(float4* __restrict__ ptable) {
    const int a = threadIdx.x;
    const int pos = blockIdx.x;
    if (a >= NA) return;
    const float step = (float)(M_PI / (double)NA);
    float s, c;
    sincosf((float)a * step, &s, &c);
    const int bx = pos & 7, by = pos >> 3;
    const float x0 = (float)(bx * TW) - 255.5f;
    const float x1 = x0 + (float)(TW - 1);
    const float y0 = (float)(by * TH) - 255.5f;
    // s >= 0 for angles in [0, pi): min over y at y0.
    const float tmin = 511.5f + fminf(x0 * c, x1 * c) + y0 * s;
    const int base = (int)floorf(tmin) - 1;
    ptable[pos * NA + a] = make_float4(c, s, 511.5f - (float)base,
                                       __int_as_float(a * ND + base));
}

// ---------------------------------------------------------------------------
// Kernel 1: ramp filter via in-LDS Stockham RADIX-4 FFT (fp32), 5 passes per
// direction, XOR granule swizzle SZ on all LDS indices (R3: -30us).
// R4 addition: for the GLOBAL-GATHER pairs (p in {2,3,6,7}) the epilogue
// also writes the duplicated 16B-aligned gather buffer
//   G[duo][a][i] = (f_p2[i], f_p2[i+1], f_p3[i], f_p3[i+1])   (duo: 0=2/3, 1=6/7)
// p=even writes .xy (uint2 at +0, 16B aligned), p=odd writes .zw (+8).
// This gives backproj a single aligned global_load_dwordx4 per 4 batches.
// ---------------------------------------------------------------------------
#define SZ(i) ((i) ^ (((i) >> 4) & 15))

__device__ __forceinline__ float2 cmul(float2 w, float2 v) {
    return make_float2(w.x * v.x - w.y * v.y, w.x * v.y + w.y * v.x);
}
__device__ __forceinline__ float2 cmulc(float2 w, float2 v) {  // conj(w)*v
    return make_float2(w.x * v.x + w.y * v.y, w.x * v.y - w.y * v.x);
}

__global__ __launch_bounds__(256) void filter_kernel(const float* __restrict__ sino,
                                                     const float* __restrict__ filt,
                                                     uint32_t* __restrict__ packed,
                                                     uint4* __restrict__ gbuf) {
    __shared__ float2 bufA[ND];
    __shared__ float2 bufB[ND];
    __shared__ float2 tw4[768];   // tw4[t] = exp(-2*pi*i*t/ND), t < 3N/4

    const int tid = threadIdx.x;
    const int a = blockIdx.x;       // angle
    const int p = blockIdx.y;       // batch pair
    const float* __restrict__ xa = sino + ((size_t)(2 * p) * NA + a) * ND;
    const float* __restrict__ xb = xa + (size_t)NA * ND;
    uint32_t* __restrict__ yo = packed + ((size_t)(2 * p) * NA + a) * ND;

    #pragma unroll
    for (int i = 0; i < ND; i += 256)
        bufA[SZ(i + tid)] = make_float2(xa[i + tid], xb[i + tid]);
    #pragma unroll
    for (int i = 0; i < 768; i += 256) {
        int m = i + tid;
        float ang = (float)(-2.0 * M_PI / (double)ND) * (float)m;
        float s, c;
        sincosf(ang, &s, &c);
        tw4[SZ(m)] = make_float2(c, s);
    }
    __syncthreads();

    float2* src = bufA;
    float2* dst = bufB;

    // forward FFT: Stockham radix-4, Ns = 1,4,16,64,256
    for (int Ns = 1; Ns < ND; Ns <<= 2) {
        const int j = tid;
        const int m = j & (Ns - 1);
        const int tstep = (ND / 4) / Ns;
        float2 u0 = src[SZ(j)];
        float2 x1 = src[SZ(j + 256)];
        float2 x2 = src[SZ(j + 512)];
        float2 x3 = src[SZ(j + 768)];
        float2 w1 = tw4[SZ(m * tstep)];
        float2 w2 = tw4[SZ(2 * m * tstep)];
        float2 w3 = tw4[SZ(3 * m * tstep)];
        float2 u1 = cmul(w1, x1), u2 = cmul(w2, x2), u3 = cmul(w3, x3);
        float2 A  = make_float2(u0.x + u2.x, u0.y + u2.y);
        float2 Bb = make_float2(u0.x - u2.x, u0.y - u2.y);
        float2 C  = make_float2(u1.x + u3.x, u1.y + u3.y);
        float2 D  = make_float2(u1.x - u3.x, u1.y - u3.y);
        const int d = ((j & ~(Ns - 1)) << 2) + m;
        dst[SZ(d)]          = make_float2(A.x + C.x, A.y + C.y);
        dst[SZ(d + Ns)]     = make_float2(Bb.x + D.y, Bb.y - D.x);   // -i*D
        dst[SZ(d + 2 * Ns)] = make_float2(A.x - C.x, A.y - C.y);
        dst[SZ(d + 3 * Ns)] = make_float2(Bb.x - D.y, Bb.y + D.x);   // +i*D
        __syncthreads();
        float2* tmp = src; src = dst; dst = tmp;
    }

    // multiply by real filter, with 1/ND folded in
    const float SCALE = 1.0f / (float)ND;
    #pragma unroll
    for (int i = 0; i < ND; i += 256) {
        float f = filt[i + tid] * SCALE;
        src[SZ(i + tid)].x *= f;
        src[SZ(i + tid)].y *= f;
    }
    __syncthreads();

    // inverse FFT: conjugated twiddles, y1/y3 swapped (+i/-i)
    for (int Ns = 1; Ns < ND; Ns <<= 2) {
        const int j = tid;
        const int m = j & (Ns - 1);
        const int tstep = (ND / 4) / Ns;
        float2 u0 = src[SZ(j)];
        float2 x1 = src[SZ(j + 256)];
        float2 x2 = src[SZ(j + 512)];
        float2 x3 = src[SZ(j + 768)];
        float2 w1 = tw4[SZ(m * tstep)];
        float2 w2 = tw4[SZ(2 * m * tstep)];
        float2 w3 = tw4[SZ(3 * m * tstep)];
        float2 u1 = cmulc(w1, x1), u2 = cmulc(w2, x2), u3 = cmulc(w3, x3);
        float2 A  = make_float2(u0.x + u2.x, u0.y + u2.y);
        float2 Bb = make_float2(u0.x - u2.x, u0.y - u2.y);
        float2 C  = make_float2(u1.x + u3.x, u1.y + u3.y);
        float2 D  = make_float2(u1.x - u3.x, u1.y - u3.y);
        const int d = ((j & ~(Ns - 1)) << 2) + m;
        dst[SZ(d)]          = make_float2(A.x + C.x, A.y + C.y);
        dst[SZ(d + Ns)]     = make_float2(Bb.x - D.y, Bb.y + D.x);   // +i*D
        dst[SZ(d + 2 * Ns)] = make_float2(A.x - C.x, A.y - C.y);
        dst[SZ(d + 3 * Ns)] = make_float2(Bb.x + D.y, Bb.y - D.x);   // -i*D
        __syncthreads();
        float2* tmp = src; src = dst; dst = tmp;
    }

    const int duo = (p == 2 || p == 3) ? 0 : (p == 6 || p == 7) ? 1 : -1;
    #pragma unroll
    for (int i = 0; i < ND; i += 256) {
        const int idx = i + tid;
        float2 v = src[SZ(idx)];
        uint32_t u = pkrtz_u32(v.x, v.y);
        yo[idx] = u;
        if (gbuf != nullptr && duo >= 0) {
            float2 vn = src[SZ(min(idx + 1, ND - 1))];
            uint32_t un = pkrtz_u32(vn.x, vn.y);
            char* e = (char*)(gbuf + ((size_t)duo * NA + a) * ND + idx)
                      + ((p & 1) ? 8 : 0);
            *(uint2*)e = make_uint2(u, un);
        }
    }
}

// ---------------------------------------------------------------------------
// Kernel 2 (R4): hybrid-pipe backprojection. 64x8 tile x 8 batches per
// 256-thread block (1024 blocks -> 4/CU). R3 analysis: kernel sits at the
// LDS-pipe bandwidth floor (18 b128 wave-ops/block-angle ~ 864cyc/CU-angle
// = 260us; conflicts span-invariant). R4 splits the 8 batches across TWO
// pipes that run concurrently:
//   pairs 4bz+0,4bz+1 (batches 0-3): LDS window as before, 1 ds_read_b128
//     per thread-k; staged by threads 0..67 in the 4-phase double buffer.
//   pairs 4bz+2,4bz+3 (batches 4-7): ONE global_load_dwordx4 per thread-k
//     from the duplicated gather buffer G (built by the filter). All 16B
//     used: (f2[i0],f2[i0+1],f3[i0],f3[i0+1]); df via __hsub2 at consume
//     (bit-identical to the staged-df arithmetic). Intra-wave i0 span ~12
//     entries -> ~3 cache lines per wave-load, L1-resident across waves.
// LDS wave-ops/block-angle: 18 -> 10; TA carries 8 gather-loads; VALU +2
// hsub2/thread-k. Pipes overlap -> predicted ~220us.
// ---------------------------------------------------------------------------
__global__ __launch_bounds__(256, 4) void backproj_kernel(const uint32_t* __restrict__ packed,
                                                          const uint4* __restrict__ gbuf,
                                                          const float4* __restrict__ ptable,
                                                          float* __restrict__ img) {
    // win[ph][i]: pairs 4bz+0, 4bz+1; entry = (fA, dfA, fB, dfB) fp16-packed
    // 4*68*16B = 4352 B
    __shared__ __align__(16) uint4 win[4][WINN];

    const int tid = threadIdx.x;
    const int bx = blockIdx.x, by = blockIdx.y, bz = blockIdx.z;

    const float4* __restrict__ pt = ptable + (size_t)((by << 3) + bx) * NA;
    const uint4* __restrict__ Gb = gbuf + (size_t)bz * NA * ND;

    // staging: threads 0..67 stage pairs 4bz+0 (sbA), 4bz+1 (sbB)
    const bool stg = tid < WINN;
    const uint32_t* __restrict__ sbA =
        packed + (size_t)(2 * (4 * bz)) * NA * ND + tid;
    const uint32_t* __restrict__ sbB = sbA + (size_t)2 * NA * ND;
    uint4* const wptr = &win[0][tid < WINN ? tid : 0];

    // lane map: wave = 8x x 8y; thread's k-subtiles at x = 16*wid + 8k + x7
    const int lane = tid & 63;
    const int wid  = tid >> 6;
    const int tx0  = (wid << 4) + (lane & 7);         // k adds 8
    const int ty   = lane >> 3;                       // 0..7
    const float px  = (float)(bx * TW + tx0) - 255.5f;
    const float pyf = (float)(by * TH + ty)  - 255.5f;

    float accf[8][PXT];
    __half2 hacc01[PXT], hacc23[PXT], hacc45[PXT], hacc67[PXT];
    #pragma unroll
    for (int k = 0; k < PXT; k++) {
        #pragma unroll
        for (int b = 0; b < 8; b++) accf[b][k] = 0.0f;
        hacc01[k] = u32_to_h2(0u); hacc23[k] = u32_to_h2(0u);
        hacc45[k] = u32_to_h2(0u); hacc67[k] = u32_to_h2(0u);
    }

    auto stage_load = [&](float4 P, uint2& wA, uint2& wB) {
        const int off = __float_as_int(P.w);
        const uint32_t* pa = sbA + off;
        const uint32_t* pb = sbB + off;
        wA = make_uint2(pa[0], pa[1]);
        wB = make_uint2(pb[0], pb[1]);
    };
    auto stage_write = [&](int ph, uint2 wA, uint2 wB) {
        wptr[ph * WINN] = make_uint4(
            wA.x, h2_to_u32(__hsub2(u32_to_h2(wA.y), u32_to_h2(wA.x))),
            wB.x, h2_to_u32(__hsub2(u32_to_h2(wB.y), u32_to_h2(wB.x))));
    };
    auto compute = [&](float4 P, int ph) {
        const float tb = fmaf(px, P.x, fmaf(pyf, P.y, P.z));
        #pragma unroll
        for (int k = 0; k < PXT; k++) {
            float t  = fmaf((float)(8 * k), P.x, tb);  // x-step 8 per k
            int   i0 = (int)t;                    // t > 0 -> trunc == floor
#if __has_builtin(__builtin_amdgcn_fractf)
            float w  = __builtin_amdgcn_fractf(t);
#else
            float w  = t - (float)i0;
#endif
            __half2 wh2 = u32_to_h2(pkrtz_u32(w, w));   // one pkrtz
            const uint4 qA = win[ph][i0];                       // LDS pipe
            const uint4 gv = Gb[__float_as_int(P.w) + i0];      // TA/L1 pipe
            hacc01[k] = __hfma2(wh2, u32_to_h2(qA.y), __hadd2(hacc01[k], u32_to_h2(qA.x)));
            hacc23[k] = __hfma2(wh2, u32_to_h2(qA.w), __hadd2(hacc23[k], u32_to_h2(qA.z)));
            __half2 F2 = u32_to_h2(gv.x), F2n = u32_to_h2(gv.y);
            hacc45[k] = __hfma2(wh2, __hsub2(F2n, F2), __hadd2(hacc45[k], F2));
            __half2 F3 = u32_to_h2(gv.z), F3n = u32_to_h2(gv.w);
            hacc67[k] = __hfma2(wh2, __hsub2(F3n, F3), __hadd2(hacc67[k], F3));
        }
    };

    // prologue: stage angles 0,1 into phases 0,1; hold raw loads of 2,3
    uint2 h2A = make_uint2(0, 0), h2B = make_uint2(0, 0);
    uint2 h3A = make_uint2(0, 0), h3B = make_uint2(0, 0);
    if (stg) {
        uint2 wA, wB;
        stage_load(pt[0], wA, wB);  stage_write(0, wA, wB);
        stage_load(pt[1], wA, wB);  stage_write(1, wA, wB);
        stage_load(pt[2], h2A, h2B);
        stage_load(pt[3], h3A, h3B);
    }
    __syncthreads();

    for (int g = 0; g < NA; g += GROUP) {
        #pragma unroll 1
        for (int it = 0; it < GROUP / 4; it++) {
            const int a = g + it * 4;
            // params a..a+7 via uniform s_load (a+4.. clamped; only .w used
            // for staging addresses of angles that are never computed OOB)
            const float4 P0 = pt[a],     P1 = pt[a + 1];
            const float4 P2 = pt[a + 2], P3 = pt[a + 3];
            const float4 P4 = pt[min(a + 4, NA - 1)], P5 = pt[min(a + 5, NA - 1)];
            const float4 P6 = pt[min(a + 6, NA - 1)], P7 = pt[min(a + 7, NA - 1)];

            // ---- sub-round A: compute a, a+1 (ph 0,1) ----
            uint2 l4A = make_uint2(0, 0), l4B = make_uint2(0, 0);
            uint2 l5A = make_uint2(0, 0), l5B = make_uint2(0, 0);
            if (stg) {
                stage_load(P4, l4A, l4B);        // angle a+4 (consumed in B)
                stage_load(P5, l5A, l5B);        // angle a+5
                stage_write(2, h2A, h2B);        // angle a+2 -> ph2
                stage_write(3, h3A, h3B);        // angle a+3 -> ph3
            }
            compute(P0, 0);
            compute(P1, 1);
            __syncthreads();

            // ---- sub-round B: compute a+2, a+3 (ph 2,3) ----
            uint2 l6A = make_uint2(0, 0), l6B = make_uint2(0, 0);
            uint2 l7A = make_uint2(0, 0), l7B = make_uint2(0, 0);
            if (stg) {
                stage_load(P6, l6A, l6B);        // angle a+6 (held to next it)
                stage_load(P7, l7A, l7B);        // angle a+7
                stage_write(0, l4A, l4B);        // angle a+4 -> ph0
                stage_write(1, l5A, l5B);        // angle a+5 -> ph1
            }
            compute(P2, 2);
            compute(P3, 3);
            h2A = l6A; h2B = l6B; h3A = l7A; h3B = l7B;
            __syncthreads();
        }
        // flush fp16 group accumulators into fp32
        #pragma unroll
        for (int k = 0; k < PXT; k++) {
            float2 v01 = __half22float2(hacc01[k]);
            float2 v23 = __half22float2(hacc23[k]);
            float2 v45 = __half22float2(hacc45[k]);
            float2 v67 = __half22float2(hacc67[k]);
            accf[0][k] += v01.x; accf[1][k] += v01.y;
            accf[2][k] += v23.x; accf[3][k] += v23.y;
            accf[4][k] += v45.x; accf[5][k] += v45.y;
            accf[6][k] += v67.x; accf[7][k] += v67.y;
            hacc01[k] = u32_to_h2(0u); hacc23[k] = u32_to_h2(0u);
            hacc45[k] = u32_to_h2(0u); hacc67[k] = u32_to_h2(0u);
        }
    }

    const float SCALE = (float)(M_PI / (double)NA);
    const size_t bstride = (size_t)NH * NW;
    // pixel of k-subtile: row by*TH + ty, col bx*TW + tx0 + 8k
    size_t o0 = (((size_t)(bz * NBT) * NH) + (by * TH + ty)) * NW + (bx * TW + tx0);
    #pragma unroll
    for (int k = 0; k < PXT; k++) {
        #pragma unroll
        for (int b = 0; b < 8; b++)
            img[o0 + (size_t)(8 * k) + (size_t)b * bstride] = accf[b][k] * SCALE;
    }
}

// ---------------------------------------------------------------------------
// Fallback backprojection (R3 version, all pairs via LDS) — used when the
// workspace cannot hold the gather buffer G.
// ---------------------------------------------------------------------------
__global__ __launch_bounds__(256, 4) void backproj_kernel_lds(const uint32_t* __restrict__ packed,
                                                              const float4* __restrict__ ptable,
                                                              float* __restrict__ img) {
    __shared__ __align__(16) uint4 win[2][4][WINN];

    const int tid = threadIdx.x;
    const int bx = blockIdx.x, by = blockIdx.y, bz = blockIdx.z;

    const float4* __restrict__ pt = ptable + (size_t)((by << 3) + bx) * NA;

    const bool stg = tid < 2 * WINN;
    const int sg   = (tid >= WINN) ? 1 : 0;
    const int si   = tid - sg * WINN;
    const uint32_t* __restrict__ sbA =
        packed + (size_t)(2 * (4 * bz + 2 * sg)) * NA * ND + si;
    const uint32_t* __restrict__ sbB = sbA + (size_t)2 * NA * ND;
    uint4* const wptr = &win[sg][0][si];

    const int lane = tid & 63;
    const int wid  = tid >> 6;
    const int tx0  = (wid << 4) + (lane & 7);
    const int ty   = lane >> 3;
    const float px  = (float)(bx * TW + tx0) - 255.5f;
    const float pyf = (float)(by * TH + ty)  - 255.5f;

    float accf[8][PXT];
    __half2 hacc01[PXT], hacc23[PXT], hacc45[PXT], hacc67[PXT];
    #pragma unroll
    for (int k = 0; k < PXT; k++) {
        #pragma unroll
        for (int b = 0; b < 8; b++) accf[b][k] = 0.0f;
        hacc01[k] = u32_to_h2(0u); hacc23[k] = u32_to_h2(0u);
        hacc45[k] = u32_to_h2(0u); hacc67[k] = u32_to_h2(0u);
    }

    auto stage_load = [&](float4 P, uint2& wA, uint2& wB) {
        const int off = __float_as_int(P.w);
        wA = make_uint2(sbA[off], sbA[off + 1]);
        wB = make_uint2(sbB[off], sbB[off + 1]);
    };
    auto stage_write = [&](int ph, uint2 wA, uint2 wB) {
        wptr[ph * WINN] = make_uint4(
            wA.x, h2_to_u32(__hsub2(u32_to_h2(wA.y), u32_to_h2(wA.x))),
            wB.x, h2_to_u32(__hsub2(u32_to_h2(wB.y), u32_to_h2(wB.x))));
    };
    auto compute = [&](float4 P, int ph) {
        const float tb = fmaf(px, P.x, fmaf(pyf, P.y, P.z));
        #pragma unroll
        for (int k = 0; k < PXT; k++) {
            float t  = fmaf((float)(8 * k), P.x, tb);
            int   i0 = (int)t;
#if __has_builtin(__builtin_amdgcn_fractf)
            float w  = __builtin_amdgcn_fractf(t);
#else
            float w  = t - (float)i0;
#endif
            __half2 wh2 = u32_to_h2(pkrtz_u32(w, w));
            const uint4 qA = win[0][ph][i0];
            const uint4 qB = win[1][ph][i0];
            hacc01[k] = __hfma2(wh2, u32_to_h2(qA.y), __hadd2(hacc01[k], u32_to_h2(qA.x)));
            hacc23[k] = __hfma2(wh2, u32_to_h2(qA.w), __hadd2(hacc23[k], u32_to_h2(qA.z)));
            hacc45[k] = __hfma2(wh2, u32_to_h2(qB.y), __hadd2(hacc45[k], u32_to_h2(qB.x)));
            hacc67[k] = __hfma2(wh2, u32_to_h2(qB.w), __hadd2(hacc67[k], u32_to_h2(qB.z)));
        }
    };

    uint2 h2A = make_uint2(0, 0), h2B = make_uint2(0, 0);
    uint2 h3A = make_uint2(0, 0), h3B = make_uint2(0, 0);
    if (stg) {
        uint2 wA, wB;
        stage_load(pt[0], wA, wB);  stage_write(0, wA, wB);
        stage_load(pt[1], wA, wB);  stage_write(1, wA, wB);
        stage_load(pt[2], h2A, h2B);
        stage_load(pt[3], h3A, h3B);
    }
    __syncthreads();

    for (int g = 0; g < NA; g += GROUP) {
        #pragma unroll 1
        for (int it = 0; it < GROUP / 4; it++) {
            const int a = g + it * 4;
            const float4 P0 = pt[a],     P1 = pt[a + 1];
            const float4 P2 = pt[a + 2], P3 = pt[a + 3];
            const float4 P4 = pt[min(a + 4, NA - 1)], P5 = pt[min(a + 5, NA - 1)];
            const float4 P6 = pt[min(a + 6, NA - 1)], P7 = pt[min(a + 7, NA - 1)];

            uint2 l4A = make_uint2(0, 0), l4B = make_uint2(0, 0);
            uint2 l5A = make_uint2(0, 0), l5B = make_uint2(0, 0);
            if (stg) {
                stage_load(P4, l4A, l4B);
                stage_load(P5, l5A, l5B);
                stage_write(2, h2A, h2B);
                stage_write(3, h3A, h3B);
            }
            compute(P0, 0);
            compute(P1, 1);
            __syncthreads();

            uint2 l6A = make_uint2(0, 0), l6B = make_uint2(0, 0);
            uint2 l7A = make_uint2(0, 0), l7B = make_uint2(0, 0);
            if (stg) {
                stage_load(P6, l6A, l6B);
                stage_load(P7, l7A, l7B);
                stage_write(0, l4A, l4B);
                stage_write(1, l5A, l5B);
            }
            compute(P2, 2);
            compute(P3, 3);
            h2A = l6A; h2B = l6B; h3A = l7A; h3B = l7B;
            __syncthreads();
        }
        #pragma unroll
        for (int k = 0; k < PXT; k++) {
            float2 v01 = __half22float2(hacc01[k]);
            float2 v23 = __half22float2(hacc23[k]);
            float2 v45 = __half22float2(hacc45[k]);
            float2 v67 = __half22float2(hacc67[k]);
            accf[0][k] += v01.x; accf[1][k] += v01.y;
            accf[2][k] += v23.x; accf[3][k] += v23.y;
            accf[4][k] += v45.x; accf[5][k] += v45.y;
            accf[6][k] += v67.x; accf[7][k] += v67.y;
            hacc01[k] = u32_to_h2(0u); hacc23[k] = u32_to_h2(0u);
            hacc45[k] = u32_to_h2(0u); hacc67[k] = u32_to_h2(0u);
        }
    }

    const float SCALE = (float)(M_PI / (double)NA);
    const size_t bstride = (size_t)NH * NW;
    size_t o0 = (((size_t)(bz * NBT) * NH) + (by * TH + ty)) * NW + (bx * TW + tx0);
    #pragma unroll
    for (int k = 0; k < PXT; k++) {
        #pragma unroll
        for (int b = 0; b < 8; b++)
            img[o0 + (size_t)(8 * k) + (size_t)b * bstride] = accf[b][k] * SCALE;
    }
}

// ---------------------------------------------------------------------------
extern "C" void kernel_launch(void* const* d_in, const int* in_sizes, int n_in,
                              void* d_out, int out_size, void* d_ws, size_t ws_size,
                              hipStream_t stream) {
    const float* sino = (const float*)d_in[0];
    const float* filt = (const float*)d_in[1];
    float* out = (float*)d_out;

    const size_t pack_bytes = (size_t)NB * NA * ND * sizeof(uint32_t);   // 47.2 MB
    const size_t g_bytes    = (size_t)2 * NA * ND * sizeof(uint4);       // 23.6 MB
    const size_t ptab_bytes = (size_t)512 * NA * sizeof(float4);         //  5.9 MB

    uint32_t* packed;
    uint4* gbuf = nullptr;
    float4* ptable;

    if (ws_size >= pack_bytes + g_bytes + ptab_bytes) {
        packed = (uint32_t*)d_ws;
        gbuf   = (uint4*)((char*)d_ws + pack_bytes);
        ptable = (float4*)((char*)d_ws + pack_bytes + g_bytes);
    } else if (ws_size >= pack_bytes + ptab_bytes) {
        packed = (uint32_t*)d_ws;
        ptable = (float4*)((char*)d_ws + pack_bytes);
    } else {
        // in-place pack into the input (filter writes are block-local);
        // params table in d_ws.
        packed = (uint32_t*)d_in[0];
        ptable = (float4*)d_ws;
    }

    prep_kernel<<<dim3(512), dim3(768), 0, stream>>>(ptable);
    filter_kernel<<<dim3(NA, NB / 2), dim3(256), 0, stream>>>(sino, filt, packed, gbuf);
    if (gbuf != nullptr) {
        backproj_kernel<<<dim3(NW / TW, NH / TH, NB / NBT), dim3(256), 0, stream>>>(packed, gbuf, ptable, out);
    } else {
        backproj_kernel_lds<<<dim3(NW / TW, NH / TH, NB / NBT), dim3(256), 0, stream>>>(packed, ptable, out);
    }
}